// Round 1
// baseline (945.921 us; speedup 1.0000x reference)
//
#include <hip/hip_runtime.h>
#include <hip/hip_bf16.h>

// Problem constants (from reference):
//   x:      (B=4, J=2048, M=4096) fp32  -> rows R = B*J = 8192, row-major M
//   lora_A: (N=4, D=16, M=4096)   fp32  -> ND = 64 rows, row-major M
//   lora_B: (N=4, K=4096, D=16)   fp32
//   out:    (N, B, J, K) fp32 = (n*R + row)*K + k     (512 MiB, write-bound)
//   t:      t[n][row][d] = sum_m x[row][m] * A[nd][m], nd = n*16+d  (2 MiB)

#define MDIM 4096
#define KDIM 4096
#define RDIM 8192
#define NDND 64          // N*D
#define MHALF 2048       // m-split: 2 halves
#define TPART_STRIDE (4 * RDIM * 16)  // floats per m-half partial (2 MiB)

// ---------------- Stage 1: t_partial[mh][n][row][d] = x . A^T (half-m) -----
// Grid: (256 row-chunks of 32 rows, 2 m-halves). Block: 256 threads = 4 waves.
// Wave w handles rows [rb*32 + w*8, +8); lane = nd. x-row addresses are
// wave-uniform (readfirstlane) so x can ride the scalar pipe; A rides VMEM/L1.
__global__ __launch_bounds__(256) void lora_stage1(
    const float* __restrict__ x, const float* __restrict__ A,
    float* __restrict__ tpart) {
  const int tid = threadIdx.x;
  const int nd  = tid & 63;
  const int wv  = __builtin_amdgcn_readfirstlane(tid >> 6);  // wave id, uniform
  const int rb  = blockIdx.x;   // 0..255
  const int mh  = blockIdx.y;   // 0..1
  const int row0 = rb * 32 + wv * 8;
  const int m0   = mh * MHALF;

  const float* Arow = A + (size_t)nd * MDIM + m0;
  const float* xr0  = x + (size_t)row0 * MDIM + m0;

  float acc[8];
#pragma unroll
  for (int r = 0; r < 8; ++r) acc[r] = 0.f;

#pragma unroll 2
  for (int m = 0; m < MHALF; m += 4) {
    const float4 a4 = *(const float4*)(Arow + m);
#pragma unroll
    for (int r = 0; r < 8; ++r) {
      const float4 xv = *(const float4*)(xr0 + (size_t)r * MDIM + m);  // uniform
      acc[r] = fmaf(xv.w, a4.w,
               fmaf(xv.z, a4.z,
               fmaf(xv.y, a4.y,
               fmaf(xv.x, a4.x, acc[r]))));
    }
  }

  const int n = nd >> 4, d = nd & 15;
  float* tp = tpart + (size_t)mh * TPART_STRIDE;
#pragma unroll
  for (int r = 0; r < 8; ++r) {
    tp[((size_t)n * RDIM + (row0 + r)) * 16 + d] = acc[r];
  }
}

// ---------------- Stage 2: out[n][row][k] = t[n][row][:] . B[n][k][:] ------
// Grid: (4 k-tiles of 1024, N=4, 256 row-chunks of 32). Block: 256 threads.
// Thread owns 4 consecutive k (float4 store): B frag 4x16 in 64 VGPRs,
// reused across 32 rows. t loads are wave-uniform (broadcast).
__global__ __launch_bounds__(256) void lora_stage2(
    const float* __restrict__ tpart, const float* __restrict__ Bm,
    float* __restrict__ out) {
  const int tid = threadIdx.x;
  const int kb  = blockIdx.x;   // 0..3
  const int n   = blockIdx.y;   // 0..3
  const int rc  = blockIdx.z;   // 0..255
  const int kk  = kb * 1024 + tid * 4;
  const int row0 = rc * 32;

  // B fragment: rows kk..kk+3, 16 d each (contiguous 256B per thread, coalesced)
  const float* Bn = Bm + ((size_t)n * KDIM + kk) * 16;
  float4 b[4][4];
#pragma unroll
  for (int i = 0; i < 4; ++i) {
#pragma unroll
    for (int q = 0; q < 4; ++q) {
      b[i][q] = *(const float4*)(Bn + i * 16 + q * 4);
    }
  }

  const float* t0 = tpart + ((size_t)n * RDIM + row0) * 16;
  const float* t1 = t0 + TPART_STRIDE;
  float* orow = out + ((size_t)n * RDIM + row0) * KDIM + kk;

  for (int r = 0; r < 32; ++r) {
    float4 tv[4];
#pragma unroll
    for (int q = 0; q < 4; ++q) {
      const float4 u = *(const float4*)(t0 + r * 16 + q * 4);  // uniform
      const float4 v = *(const float4*)(t1 + r * 16 + q * 4);  // uniform
      tv[q].x = u.x + v.x;
      tv[q].y = u.y + v.y;
      tv[q].z = u.z + v.z;
      tv[q].w = u.w + v.w;
    }
    float4 o;
    float* op = (float*)&o;
#pragma unroll
    for (int i = 0; i < 4; ++i) {
      float s = 0.f;
#pragma unroll
      for (int q = 0; q < 4; ++q) {
        s = fmaf(tv[q].x, b[i][q].x, s);
        s = fmaf(tv[q].y, b[i][q].y, s);
        s = fmaf(tv[q].z, b[i][q].z, s);
        s = fmaf(tv[q].w, b[i][q].w, s);
      }
      op[i] = s;
    }
    *(float4*)(orow + (size_t)r * KDIM) = o;
  }
}

extern "C" void kernel_launch(void* const* d_in, const int* in_sizes, int n_in,
                              void* d_out, int out_size, void* d_ws, size_t ws_size,
                              hipStream_t stream) {
  const float* x  = (const float*)d_in[0];   // 4*2048*4096
  const float* A  = (const float*)d_in[1];   // 4*16*4096
  const float* Bm = (const float*)d_in[2];   // 4*4096*16
  float* out   = (float*)d_out;              // 4*4*2048*4096
  float* tpart = (float*)d_ws;               // 2 * 2 MiB partials

  dim3 g1(256, 2, 1);
  lora_stage1<<<g1, 256, 0, stream>>>(x, A, tpart);

  dim3 g2(4, 4, 256);
  lora_stage2<<<g2, 256, 0, stream>>>(tpart, Bm, out);
}